// Round 1
// baseline (48.259 us; speedup 1.0000x reference)
//
#include <hip/hip_runtime.h>

// Reference collapses: softmax over a size-1 axis => l == 1 everywhere, so
//   out[b, a, d] = sum_{t=0}^{T-1} value[a, b, t, d]
// Pure memory-bound reduction over 256 MiB of fp32.

constexpr int A_ = 4, B_ = 16, T_ = 1024, D_ = 1024;
constexpr int TC = 16;              // T-chunks per (a,b) pair
constexpr int TCHUNK = T_ / TC;     // 64
constexpr int STRIDE4 = D_ / 4;     // float4 stride between consecutive t

// Pass 1: each block = one (ab, tc) pair; 256 threads x float4 cover full D.
// Partial sums -> ws[blk * D + d].
__global__ __launch_bounds__(256) void wa_partial(const float* __restrict__ value,
                                                  float* __restrict__ ws) {
    const int blk = blockIdx.x;          // 0 .. A*B*TC-1
    const int tc  = blk % TC;
    const int ab  = blk / TC;
    const size_t base = ((size_t)ab * T_ + (size_t)tc * TCHUNK) * D_;
    const float4* vp = reinterpret_cast<const float4*>(value + base) + threadIdx.x;

    float4 a0{0.f,0.f,0.f,0.f}, a1{0.f,0.f,0.f,0.f};
    float4 a2{0.f,0.f,0.f,0.f}, a3{0.f,0.f,0.f,0.f};

    for (int t = 0; t < TCHUNK; t += 4) {
        float4 v0 = vp[(size_t)(t + 0) * STRIDE4];
        float4 v1 = vp[(size_t)(t + 1) * STRIDE4];
        float4 v2 = vp[(size_t)(t + 2) * STRIDE4];
        float4 v3 = vp[(size_t)(t + 3) * STRIDE4];
        a0.x += v0.x; a0.y += v0.y; a0.z += v0.z; a0.w += v0.w;
        a1.x += v1.x; a1.y += v1.y; a1.z += v1.z; a1.w += v1.w;
        a2.x += v2.x; a2.y += v2.y; a2.z += v2.z; a2.w += v2.w;
        a3.x += v3.x; a3.y += v3.y; a3.z += v3.z; a3.w += v3.w;
    }
    float4 s;
    s.x = (a0.x + a1.x) + (a2.x + a3.x);
    s.y = (a0.y + a1.y) + (a2.y + a3.y);
    s.z = (a0.z + a1.z) + (a2.z + a3.z);
    s.w = (a0.w + a1.w) + (a2.w + a3.w);
    reinterpret_cast<float4*>(ws + (size_t)blk * D_)[threadIdx.x] = s;
}

// Pass 2: fold TC partials per (a,b); write transposed out[(b*A + a)*D + d].
__global__ __launch_bounds__(256) void wa_final(const float* __restrict__ ws,
                                                float* __restrict__ out) {
    const int ab = blockIdx.x;           // 0 .. A*B-1
    const int a  = ab / B_;
    const int b  = ab % B_;
    float4 acc{0.f,0.f,0.f,0.f};
    for (int tc = 0; tc < TC; ++tc) {
        float4 v = reinterpret_cast<const float4*>(ws + ((size_t)(ab * TC + tc)) * D_)[threadIdx.x];
        acc.x += v.x; acc.y += v.y; acc.z += v.z; acc.w += v.w;
    }
    reinterpret_cast<float4*>(out + ((size_t)(b * A_ + a)) * D_)[threadIdx.x] = acc;
}

// Fallback (ws too small): one block per (a,b), full-T loop, direct write.
__global__ __launch_bounds__(256) void wa_direct(const float* __restrict__ value,
                                                 float* __restrict__ out) {
    const int ab = blockIdx.x;
    const int a  = ab / B_;
    const int b  = ab % B_;
    const size_t base = (size_t)ab * T_ * D_;
    const float4* vp = reinterpret_cast<const float4*>(value + base) + threadIdx.x;
    float4 a0{0.f,0.f,0.f,0.f}, a1{0.f,0.f,0.f,0.f};
    float4 a2{0.f,0.f,0.f,0.f}, a3{0.f,0.f,0.f,0.f};
    for (int t = 0; t < T_; t += 4) {
        float4 v0 = vp[(size_t)(t + 0) * STRIDE4];
        float4 v1 = vp[(size_t)(t + 1) * STRIDE4];
        float4 v2 = vp[(size_t)(t + 2) * STRIDE4];
        float4 v3 = vp[(size_t)(t + 3) * STRIDE4];
        a0.x += v0.x; a0.y += v0.y; a0.z += v0.z; a0.w += v0.w;
        a1.x += v1.x; a1.y += v1.y; a1.z += v1.z; a1.w += v1.w;
        a2.x += v2.x; a2.y += v2.y; a2.z += v2.z; a2.w += v2.w;
        a3.x += v3.x; a3.y += v3.y; a3.z += v3.z; a3.w += v3.w;
    }
    float4 s;
    s.x = (a0.x + a1.x) + (a2.x + a3.x);
    s.y = (a0.y + a1.y) + (a2.y + a3.y);
    s.z = (a0.z + a1.z) + (a2.z + a3.z);
    s.w = (a0.w + a1.w) + (a2.w + a3.w);
    reinterpret_cast<float4*>(out + ((size_t)(b * A_ + a)) * D_)[threadIdx.x] = s;
}

extern "C" void kernel_launch(void* const* d_in, const int* in_sizes, int n_in,
                              void* d_out, int out_size, void* d_ws, size_t ws_size,
                              hipStream_t stream) {
    const float* value = (const float*)d_in[1];   // (A, B, T, D) fp32
    float* out = (float*)d_out;                   // (B, A, D) fp32
    const size_t need = (size_t)A_ * B_ * TC * D_ * sizeof(float);  // 4 MiB
    if (ws_size >= need) {
        float* ws = (float*)d_ws;
        wa_partial<<<A_ * B_ * TC, 256, 0, stream>>>(value, ws);
        wa_final<<<A_ * B_, 256, 0, stream>>>(ws, out);
    } else {
        wa_direct<<<A_ * B_, 256, 0, stream>>>(value, out);
    }
}

// Round 2
// 43.056 us; speedup vs baseline: 1.1208x; 1.1208x over previous
//
#include <hip/hip_runtime.h>

// Reference collapses: softmax over a size-1 axis => l == 1 everywhere, so
//   out[b, a, d] = sum_{t=0}^{T-1} value[a, b, t, d]
// Pure memory-bound fp32 reduction over 256 MiB. Single fused kernel:
// grid = A*B*4 blocks; each block owns one (a,b, 256-float D-stripe);
// 16 t-groups x 64 lanes sum 64 rows each; LDS tree folds the 16 partials.

constexpr int A_ = 4, B_ = 16, T_ = 1024, D_ = 1024;
constexpr int NCH  = 4;           // D-chunks per (a,b)
constexpr int CHW  = D_ / NCH;    // 256 floats per chunk (= 1 KiB = one wave's float4)
constexpr int NG   = 16;          // t-groups per block
constexpr int GT   = CHW / 4;     // 64 threads per group (float4 each)
constexpr int ROWS = T_ / NG;     // 64 rows per group
constexpr int STRIDE4 = D_ / 4;   // float4 stride between consecutive t

__global__ __launch_bounds__(1024) void wa_fused(const float* __restrict__ value,
                                                 float* __restrict__ out) {
    const int blk = blockIdx.x;            // 0 .. A*B*NCH-1
    const int ch  = blk % NCH;
    const int ab  = blk / NCH;
    const int a   = ab / B_;
    const int b   = ab % B_;
    const int t   = threadIdx.x % GT;      // lane within group (d index)
    const int g   = threadIdx.x / GT;      // t-group 0..15

    const float4* vp = reinterpret_cast<const float4*>(
        value + (size_t)ab * T_ * D_ + (size_t)g * ROWS * D_ + (size_t)ch * CHW) + t;

    float4 a0{0.f,0.f,0.f,0.f}, a1{0.f,0.f,0.f,0.f};
    float4 a2{0.f,0.f,0.f,0.f}, a3{0.f,0.f,0.f,0.f};
    for (int r = 0; r < ROWS; r += 4) {
        float4 v0 = vp[(size_t)(r + 0) * STRIDE4];
        float4 v1 = vp[(size_t)(r + 1) * STRIDE4];
        float4 v2 = vp[(size_t)(r + 2) * STRIDE4];
        float4 v3 = vp[(size_t)(r + 3) * STRIDE4];
        a0.x += v0.x; a0.y += v0.y; a0.z += v0.z; a0.w += v0.w;
        a1.x += v1.x; a1.y += v1.y; a1.z += v1.z; a1.w += v1.w;
        a2.x += v2.x; a2.y += v2.y; a2.z += v2.z; a2.w += v2.w;
        a3.x += v3.x; a3.y += v3.y; a3.z += v3.z; a3.w += v3.w;
    }
    float4 s;
    s.x = (a0.x + a1.x) + (a2.x + a3.x);
    s.y = (a0.y + a1.y) + (a2.y + a3.y);
    s.z = (a0.z + a1.z) + (a2.z + a3.z);
    s.w = (a0.w + a1.w) + (a2.w + a3.w);

    __shared__ float4 lds[NG * GT];        // 16 KiB
    lds[g * GT + t] = s;
    __syncthreads();
    #pragma unroll
    for (int sg = NG / 2; sg >= 1; sg >>= 1) {
        if (g < sg) {
            float4 o = lds[(g + sg) * GT + t];
            float4 m = lds[g * GT + t];
            m.x += o.x; m.y += o.y; m.z += o.z; m.w += o.w;
            lds[g * GT + t] = m;
        }
        __syncthreads();
    }
    if (g == 0) {
        reinterpret_cast<float4*>(
            out + ((size_t)(b * A_ + a)) * D_ + (size_t)ch * CHW)[t] = lds[t];
    }
}

extern "C" void kernel_launch(void* const* d_in, const int* in_sizes, int n_in,
                              void* d_out, int out_size, void* d_ws, size_t ws_size,
                              hipStream_t stream) {
    const float* value = (const float*)d_in[1];   // (A, B, T, D) fp32
    float* out = (float*)d_out;                   // (B, A, D) fp32
    wa_fused<<<A_ * B_ * NCH, 1024, 0, stream>>>(value, out);
}